// Round 6
// baseline (785547.363 us; speedup 1.0000x reference)
//
#include <hip/hip_runtime.h>
#include <math.h>

// HierarchicalRecursiveTRM on MI355X — round 6.
// 8 teams x (2 batches, 32 WGs). Weights f32 in LDS (1/32 rows per WG).
// Exchange: tag-embedded 8B words {f32 val, u32 stage tag}; consumers poll the
// data words directly. XCD-uniform teams (runtime HW_REG_XCC_ID check):
// producer stores sc0 (write-through to local L2); consumer polls with
// buffer_inv (vL1 invalidate) + sc0 load -> served by local L2. Round 5 proved
// sc0 loads can spin forever on a stale vL1 line (no probes) — the inv fixes
// that. Every 64th retry: one sc0sc1 probe (IF) whose own data is used if
// ready — liveness insurance under any cache model. Non-uniform teams:
// sc0 sc1 both sides (IF-coherent, round-3-proven).

#define NB   16
#define SEQ  4096
#define TEAMS 8
#define WPT  32
#define BPT  2
#define NTH  256

typedef unsigned u32x2 __attribute__((ext_vector_type(2)));
typedef unsigned u32x4 __attribute__((ext_vector_type(4)));

__device__ __forceinline__ float fexp(float v){ return __builtin_amdgcn_exp2f(v*1.44269504089f); }
__device__ __forceinline__ float sigf(float v){ return __builtin_amdgcn_rcpf(1.f + fexp(-v)); }
__device__ __forceinline__ float ftanh(float v){ return 2.f*sigf(2.f*v) - 1.f; }

// startup-only agent-scope relaxed helpers
__device__ __forceinline__ void st_ag(unsigned* p, unsigned v){
  __hip_atomic_store(p, v, __ATOMIC_RELAXED, __HIP_MEMORY_SCOPE_AGENT);
}
__device__ __forceinline__ unsigned ld_ag(const unsigned* p){
  return __hip_atomic_load(p, __ATOMIC_RELAXED, __HIP_MEMORY_SCOPE_AGENT);
}

__device__ __forceinline__ unsigned long long packw(float v, unsigned tag){
  return ((unsigned long long)tag << 32) | (unsigned long long)__float_as_uint(v);
}

__device__ __forceinline__ void st64(unsigned long long* p, unsigned long long v, bool fast){
  if (fast) asm volatile("global_store_dwordx2 %0, %1, off sc0"     :: "v"(p), "v"(v) : "memory");
  else      asm volatile("global_store_dwordx2 %0, %1, off sc0 sc1" :: "v"(p), "v"(v) : "memory");
}

// Raw WG barrier: LDS ordering only, no vmcnt drain.
#define WGBAR() asm volatile("s_waitcnt lgkmcnt(0)\n\ts_barrier" ::: "memory")

__device__ __forceinline__ float poll1(const unsigned long long* p, unsigned tag, bool fast){
  u32x2 w;
  if (fast){
    int spin = 0;
    for(;;){
      asm volatile("buffer_inv\n\t"
                   "global_load_dwordx2 %0, %1, off sc0\n\ts_waitcnt vmcnt(0)"
                   : "=&v"(w) : "v"(p) : "memory");
      if (w.y >= tag) break;
      if ((++spin & 63) == 0){
        asm volatile("global_load_dwordx2 %0, %1, off sc0 sc1\n\ts_waitcnt vmcnt(0)"
                     : "=&v"(w) : "v"(p) : "memory");
        if (w.y >= tag) break;
      }
    }
  } else {
    for(;;){
      asm volatile("global_load_dwordx2 %0, %1, off sc0 sc1\n\ts_waitcnt vmcnt(0)"
                   : "=&v"(w) : "v"(p) : "memory");
      if (w.y >= tag) break;
      __builtin_amdgcn_s_sleep(1);
    }
  }
  return __uint_as_float(w.x);
}

__device__ __forceinline__ float2 poll2(const unsigned long long* p, unsigned tag, bool fast){
  u32x4 w;
  if (fast){
    int spin = 0;
    for(;;){
      asm volatile("buffer_inv\n\t"
                   "global_load_dwordx4 %0, %1, off sc0\n\ts_waitcnt vmcnt(0)"
                   : "=&v"(w) : "v"(p) : "memory");
      if (w.y >= tag && w.w >= tag) break;
      if ((++spin & 63) == 0){
        asm volatile("global_load_dwordx4 %0, %1, off sc0 sc1\n\ts_waitcnt vmcnt(0)"
                     : "=&v"(w) : "v"(p) : "memory");
        if (w.y >= tag && w.w >= tag) break;
      }
    }
  } else {
    for(;;){
      asm volatile("global_load_dwordx4 %0, %1, off sc0 sc1\n\ts_waitcnt vmcnt(0)"
                   : "=&v"(w) : "v"(p) : "memory");
      if (w.y >= tag && w.w >= tag) break;
      __builtin_amdgcn_s_sleep(1);
    }
  }
  float2 r; r.x = __uint_as_float(w.x); r.y = __uint_as_float(w.z); return r;
}

__device__ __forceinline__ float4 poll4(const unsigned long long* p, unsigned tag, bool fast){
  u32x4 w0, w1;
  if (fast){
    int spin = 0;
    for(;;){
      asm volatile("buffer_inv\n\t"
                   "global_load_dwordx4 %0, %2, off sc0\n\t"
                   "global_load_dwordx4 %1, %3, off sc0\n\t"
                   "s_waitcnt vmcnt(0)"
                   : "=&v"(w0), "=&v"(w1) : "v"(p), "v"(p+2) : "memory");
      if (w0.y >= tag && w0.w >= tag && w1.y >= tag && w1.w >= tag) break;
      if ((++spin & 63) == 0){
        asm volatile("global_load_dwordx4 %0, %2, off sc0 sc1\n\t"
                     "global_load_dwordx4 %1, %3, off sc0 sc1\n\t"
                     "s_waitcnt vmcnt(0)"
                     : "=&v"(w0), "=&v"(w1) : "v"(p), "v"(p+2) : "memory");
        if (w0.y >= tag && w0.w >= tag && w1.y >= tag && w1.w >= tag) break;
      }
    }
  } else {
    for(;;){
      asm volatile("global_load_dwordx4 %0, %2, off sc0 sc1\n\t"
                   "global_load_dwordx4 %1, %3, off sc0 sc1\n\t"
                   "s_waitcnt vmcnt(0)"
                   : "=&v"(w0), "=&v"(w1) : "v"(p), "v"(p+2) : "memory");
      if (w0.y >= tag && w0.w >= tag && w1.y >= tag && w1.w >= tag) break;
      __builtin_amdgcn_s_sleep(1);
    }
  }
  float4 r;
  r.x = __uint_as_float(w0.x); r.y = __uint_as_float(w0.z);
  r.z = __uint_as_float(w1.x); r.w = __uint_as_float(w1.z);
  return r;
}

extern "C" __global__ __launch_bounds__(NTH, 1)
void trm_kernel(const float* __restrict__ x,   const float* __restrict__ h0,
                const float* __restrict__ wih, const float* __restrict__ whh,
                const float* __restrict__ bih, const float* __restrict__ bhh,
                const float* __restrict__ Lgw, const float* __restrict__ Lgb,
                const float* __restrict__ Ltw, const float* __restrict__ Ltb,
                const float* __restrict__ Luw, const float* __restrict__ Lub,
                const float* __restrict__ Hgw, const float* __restrict__ Hgb,
                const float* __restrict__ Htw, const float* __restrict__ Htb,
                const float* __restrict__ Huw, const float* __restrict__ Hub,
                float* __restrict__ out,
                unsigned* __restrict__ flg_base, unsigned long long* __restrict__ act_base)
{
  const int team = blockIdx.x & (TEAMS-1);
  const int j    = blockIdx.x / TEAMS;       // 0..31 slice id within team
  const int tid  = threadIdx.x;

  __shared__ float wgRZ[16][520];
  __shared__ float wgX[8][264];
  __shared__ float wgN[8][264];
  __shared__ float wclG[8][520], wclT[8][520];
  __shared__ float wchG[8][520], wchT[8][520];
  __shared__ float wul[8][264],  wuh[8][264];
  __shared__ float xst [BPT][256];
  __shared__ float st_o [BPT][256];
  __shared__ float st_zh[BPT][256];
  __shared__ float st_zl[BPT][256];
  __shared__ float st_h [BPT][256];
  __shared__ float bR[8],bZ[8],bX[8],bN[8],bCLg[8],bCLt[8],bCHg[8],bCHt[8],bUL[8],bUH[8];

  // ---------- one-time weight staging ----------
  {
    const int k = tid;
    for (int r=0;r<8;r++){
      const int nr = j*8+r;
      wgRZ[r][k]       = wih[(size_t)nr*256+k];
      wgRZ[r][256+k]   = whh[(size_t)nr*256+k];
      wgRZ[8+r][k]     = wih[(size_t)(256+nr)*256+k];
      wgRZ[8+r][256+k] = whh[(size_t)(256+nr)*256+k];
      wgX[r][k] = wih[(size_t)(512+nr)*256+k];
      wgN[r][k] = whh[(size_t)(512+nr)*256+k];
      wclG[r][k] = Lgw[(size_t)nr*512+k];  wclG[r][256+k] = Lgw[(size_t)nr*512+256+k];
      wclT[r][k] = Ltw[(size_t)nr*512+k];  wclT[r][256+k] = Ltw[(size_t)nr*512+256+k];
      wchG[r][k] = Hgw[(size_t)nr*512+k];  wchG[r][256+k] = Hgw[(size_t)nr*512+256+k];
      wchT[r][k] = Htw[(size_t)nr*512+k];  wchT[r][256+k] = Htw[(size_t)nr*512+256+k];
      wul[r][k] = Luw[(size_t)nr*256+k];
      wuh[r][k] = Huw[(size_t)nr*256+k];
    }
    if (tid<8){
      const int nr = j*8+tid;
      bR[tid]  = bih[nr]     + bhh[nr];
      bZ[tid]  = bih[256+nr] + bhh[256+nr];
      bX[tid]  = bih[512+nr];
      bN[tid]  = bhh[512+nr];
      bCLg[tid]= Lgb[nr];  bCLt[tid]= Ltb[nr];
      bCHg[tid]= Hgb[nr];  bCHt[tid]= Htb[nr];
      bUL[tid] = Lub[nr];  bUH[tid] = Hub[nr];
    }
    for (int u=tid; u<BPT*256; u+=NTH){
      const int b=u>>8, i=u&255;
      st_h[b][i]  = h0[(team*BPT+b)*256+i];
      st_o[b][i]  = 0.f;
      st_zh[b][i] = 0.f;
      st_zl[b][i] = 0.f;
    }
  }

  // ---------- startup: publish XCC id, team barrier, pick protocol ----------
  unsigned* flg = flg_base + team*1024;   // 4KB-separated
  unsigned xcc = 0;
  asm volatile("s_getreg_b32 %0, hwreg(HW_REG_XCC_ID)" : "=s"(xcc));
  __syncthreads();
  if (tid == 0) st_ag(flg + j, 0x100u | xcc);
  if (tid < 64){
    const int fl = tid & 31;
    for (;;){
      unsigned v = ld_ag(flg + fl);
      if (__all(v != 0)) break;
      __builtin_amdgcn_s_sleep(8);
    }
  }
  __syncthreads();
  bool fast;
  {
    unsigned v  = ld_ag(flg + (tid & 31));
    unsigned v0 = __shfl(v, 0);
    fast = __all(v == v0);
  }

  unsigned long long* actT = act_base + (size_t)team*8192;  // 64KB/team; 2 x 2048-word buffers
  unsigned kst = 0;

  // C-cell: rows [8j,8j+8): u<8 gate rows, u>=8 tanh rows. K=512=[o|hid].
  auto cstage = [&](float (*WG)[520], float (*WT)[520], float* bG, float* bT,
                    float (*hid)[256], bool wout, int tt){
    const unsigned tag = kst + 1u;
    unsigned long long* buf = actT + (kst & 1u)*2048;
    WGBAR();                                   // state writes of prev stage visible
    const int u = tid>>4, kk = tid&15, r = u&7;
    const bool isT = (u>=8);
    const float* wr = isT? WT[r] : WG[r];
    float a0=0.f, a1=0.f;
    #pragma unroll
    for (int i=0;i<16;i++){
      const float w = wr[kk+16*i];
      a0 += w*st_o[0][kk+16*i];
      a1 += w*st_o[1][kk+16*i];
    }
    #pragma unroll
    for (int i=0;i<16;i++){
      const float w = wr[256+kk+16*i];
      a0 += w*hid[0][kk+16*i];
      a1 += w*hid[1][kk+16*i];
    }
    a0 += __shfl_xor(a0,1); a0 += __shfl_xor(a0,2); a0 += __shfl_xor(a0,4); a0 += __shfl_xor(a0,8);
    a1 += __shfl_xor(a1,1); a1 += __shfl_xor(a1,2); a1 += __shfl_xor(a1,4); a1 += __shfl_xor(a1,8);
    if (kk==0){
      const float bb = isT? bT[r] : bG[r];
      const int n = j*8+r;
      st64(&buf[(0*256+n)*4 + (isT?1:0)], packw(a0+bb, tag), fast);
      st64(&buf[(1*256+n)*4 + (isT?1:0)], packw(a1+bb, tag), fast);
    }
    WGBAR();                                   // all matvec LDS reads done
    #pragma unroll
    for (int b=0;b<2;b++){
      float2 gt = poll2(&buf[(b*256+tid)*4], tag, fast);
      const float g  = sigf(gt.x);
      const float rr = ftanh(gt.y);
      const float o  = g*rr + (1.f-g)*st_o[b][tid];
      st_o[b][tid] = o;
      if (wout) out[((size_t)(team*BPT+b)*SEQ + tt)*256 + tid] = o;
    }
    kst++;
  };

  // U-cell: 8 rows/WG, 32-lane units, K=256 over st_o; dst = tanh(pre).
  auto ustage = [&](float (*W)[264], float* bU, float (*dst)[256]){
    const unsigned tag = kst + 1u;
    unsigned long long* buf = actT + (kst & 1u)*2048;
    WGBAR();
    const int u = tid>>5, kk = tid&31;
    const float* wr = W[u];
    float a0=0.f, a1=0.f;
    #pragma unroll
    for (int i=0;i<8;i++){
      const float w = wr[kk+32*i];
      a0 += w*st_o[0][kk+32*i];
      a1 += w*st_o[1][kk+32*i];
    }
    a0 += __shfl_xor(a0,1); a0 += __shfl_xor(a0,2); a0 += __shfl_xor(a0,4); a0 += __shfl_xor(a0,8); a0 += __shfl_xor(a0,16);
    a1 += __shfl_xor(a1,1); a1 += __shfl_xor(a1,2); a1 += __shfl_xor(a1,4); a1 += __shfl_xor(a1,8); a1 += __shfl_xor(a1,16);
    if (kk==0){
      const int n = j*8+u;
      st64(&buf[(0*256+n)*4], packw(a0+bU[u], tag), fast);
      st64(&buf[(1*256+n)*4], packw(a1+bU[u], tag), fast);
    }
    WGBAR();
    #pragma unroll
    for (int b=0;b<2;b++){
      const float pre = poll1(&buf[(b*256+tid)*4], tag, fast);
      dst[b][tid] = ftanh(pre);
    }
    kst++;
  };

  float px0 = x[((size_t)(team*BPT+0)*SEQ + 0)*256 + tid];
  float px1 = x[((size_t)(team*BPT+1)*SEQ + 0)*256 + tid];

  #pragma unroll 1
  for (int t=0; t<SEQ; ++t){
    // ---- GRU stage: slots {0:pr, 1:pz, 2:xn, 3:hn} per (b,i) ----
    {
      const unsigned tag = kst + 1u;
      unsigned long long* buf = actT + (kst & 1u)*2048;
      WGBAR();
      xst[0][tid] = px0;
      xst[1][tid] = px1;
      WGBAR();
      const int u = tid>>4, kk = tid&15, r = u&7;
      const int n = j*8+r;
      { // pass1: u<8 r-rows, u>=8 z-rows; K=512=[x|h]
        const bool isZ = (u>=8);
        const float* wr = wgRZ[u];
        float a0=0.f, a1=0.f;
        #pragma unroll
        for (int i=0;i<16;i++){
          const float w = wr[kk+16*i];
          a0 += w*xst[0][kk+16*i];
          a1 += w*xst[1][kk+16*i];
        }
        #pragma unroll
        for (int i=0;i<16;i++){
          const float w = wr[256+kk+16*i];
          a0 += w*st_h[0][kk+16*i];
          a1 += w*st_h[1][kk+16*i];
        }
        a0 += __shfl_xor(a0,1); a0 += __shfl_xor(a0,2); a0 += __shfl_xor(a0,4); a0 += __shfl_xor(a0,8);
        a1 += __shfl_xor(a1,1); a1 += __shfl_xor(a1,2); a1 += __shfl_xor(a1,4); a1 += __shfl_xor(a1,8);
        if (kk==0){
          const float bb = isZ? bZ[r] : bR[r];
          st64(&buf[(0*256+n)*4 + (isZ?1:0)], packw(a0+bb, tag), fast);
          st64(&buf[(1*256+n)*4 + (isZ?1:0)], packw(a1+bb, tag), fast);
        }
      }
      { // pass2: u<8 xn rows (src=x), u>=8 hn rows (src=h); K=256
        const bool isH = (u>=8);
        const float* wr = isH? wgN[r] : wgX[r];
        float (*src)[256] = isH? st_h : xst;
        float a0=0.f, a1=0.f;
        #pragma unroll
        for (int i=0;i<16;i++){
          const float w = wr[kk+16*i];
          a0 += w*src[0][kk+16*i];
          a1 += w*src[1][kk+16*i];
        }
        a0 += __shfl_xor(a0,1); a0 += __shfl_xor(a0,2); a0 += __shfl_xor(a0,4); a0 += __shfl_xor(a0,8);
        a1 += __shfl_xor(a1,1); a1 += __shfl_xor(a1,2); a1 += __shfl_xor(a1,4); a1 += __shfl_xor(a1,8);
        if (kk==0){
          const float bb = isH? bN[r] : bX[r];
          st64(&buf[(0*256+n)*4 + 2 + (isH?1:0)], packw(a0+bb, tag), fast);
          st64(&buf[(1*256+n)*4 + 2 + (isH?1:0)], packw(a1+bb, tag), fast);
        }
      }
      WGBAR();
      const bool last = (t==SEQ-1);
      #pragma unroll
      for (int b=0;b<2;b++){
        float4 p4 = poll4(&buf[(b*256+tid)*4], tag, fast);  // (pr,pz,xn,hn)
        const float rg = sigf(p4.x);
        const float zg = sigf(p4.y);
        const float ng = ftanh(p4.z + rg*p4.w);
        const float hv = (1.f-zg)*ng + zg*st_h[b][tid];
        st_h[b][tid] = hv;
        st_o[b][tid] = hv;
        if (last) out[(size_t)NB*SEQ*256 + (team*BPT+b)*256 + tid] = hv;
      }
      if (t+1 < SEQ){
        px0 = x[((size_t)(team*BPT+0)*SEQ + (t+1))*256 + tid];
        px1 = x[((size_t)(team*BPT+1)*SEQ + (t+1))*256 + tid];
      }
      kst++;
    }
    // ---- refinement: 2 H-cycles of (3x L-cell, U_L, H-cell, U_H) ----
    #pragma unroll 1
    for (int c=0;c<2;c++){
      cstage(wclG,wclT,bCLg,bCLt,st_zh,false,t);
      cstage(wclG,wclT,bCLg,bCLt,st_zh,false,t);
      cstage(wclG,wclT,bCLg,bCLt,st_zh,false,t);
      ustage(wul,bUL,st_zl);
      cstage(wchG,wchT,bCHg,bCHt,st_zl,(c==1),t);
      ustage(wuh,bUH,st_zh);
    }
  }
}

extern "C" void kernel_launch(void* const* d_in, const int* in_sizes, int n_in,
                              void* d_out, int out_size, void* d_ws, size_t ws_size,
                              hipStream_t stream)
{
  // ws: [0,32KB) team flag arrays (startup); [64KB, 64KB+512KB) tagged act buffers.
  // Zeroed every launch (tags must start below 1; harness poisons 0xAA).
  hipMemsetAsync(d_ws, 0, 65536 + TEAMS*8192*sizeof(unsigned long long), stream);
  unsigned* flg = (unsigned*)d_ws;
  unsigned long long* act = (unsigned long long*)((char*)d_ws + 65536);

  dim3 grid(TEAMS*WPT), block(NTH);
  hipLaunchKernelGGL(trm_kernel, grid, block, 0, stream,
    (const float*)d_in[0],  (const float*)d_in[1],
    (const float*)d_in[2],  (const float*)d_in[3],
    (const float*)d_in[4],  (const float*)d_in[5],
    (const float*)d_in[6],  (const float*)d_in[7],
    (const float*)d_in[8],  (const float*)d_in[9],
    (const float*)d_in[10], (const float*)d_in[11],
    (const float*)d_in[12], (const float*)d_in[13],
    (const float*)d_in[14], (const float*)d_in[15],
    (const float*)d_in[16], (const float*)d_in[17],
    (float*)d_out, flg, act);
}

// Round 7
// 139107.300 us; speedup vs baseline: 5.6471x; 5.6471x over previous
//
#include <hip/hip_runtime.h>
#include <math.h>

// HierarchicalRecursiveTRM on MI355X — round 7.
// 8 teams x (2 batches, 32 WGs). Weights f32 in LDS (1/32 rows per WG).
// Exchange: tag-embedded 8B words {f32 val, u32 stage tag}. Producer writes
// them with RELAXED AGENT atomic stores (compiler-emitted encoding — the
// round-3-proven-correct path); consumers poll the SAME words with RELAXED
// AGENT atomic loads: detection IS the data load -> one IF round trip per
// stage (round 3 had ~2.5: stores drain, flag+poll, reload).
// No XCD fast path, no sc-bit asm, no escalation (rounds 4-6 proved the
// sc0/buffer_inv model wrong twice). 2-buffer alternation race-free by
// induction: stage k+2 (overwrites buffer of stage k) can't start anywhere
// until every WG passed stage k's poll.

#define NB   16
#define SEQ  4096
#define TEAMS 8
#define WPT  32
#define BPT  2
#define NTH  256

typedef unsigned long long u64;

__device__ __forceinline__ float fexp(float v){ return __builtin_amdgcn_exp2f(v*1.44269504089f); }
__device__ __forceinline__ float sigf(float v){ return __builtin_amdgcn_rcpf(1.f + fexp(-v)); }
__device__ __forceinline__ float ftanh(float v){ return 2.f*sigf(2.f*v) - 1.f; }

__device__ __forceinline__ u64 packw(float v, unsigned tag){
  return ((u64)tag << 32) | (u64)__float_as_uint(v);
}
__device__ __forceinline__ void stw(u64* p, u64 v){
  __hip_atomic_store(p, v, __ATOMIC_RELAXED, __HIP_MEMORY_SCOPE_AGENT);
}
__device__ __forceinline__ u64 ldw(const u64* p){
  return __hip_atomic_load(p, __ATOMIC_RELAXED, __HIP_MEMORY_SCOPE_AGENT);
}

// Raw WG barrier: LDS ordering only, no vmcnt drain (stores fly free).
#define WGBAR() asm volatile("s_waitcnt lgkmcnt(0)\n\ts_barrier" ::: "memory")

__device__ __forceinline__ float poll1(const u64* p, unsigned tag){
  u64 w;
  for(;;){
    w = ldw(p);
    if ((unsigned)(w >> 32) >= tag) break;
    __builtin_amdgcn_s_sleep(1);
  }
  return __uint_as_float((unsigned)w);
}

__device__ __forceinline__ float2 poll2(const u64* p, unsigned tag){
  u64 w0, w1;
  for(;;){
    w0 = ldw(p); w1 = ldw(p+1);
    if ((unsigned)(w0 >> 32) >= tag && (unsigned)(w1 >> 32) >= tag) break;
    __builtin_amdgcn_s_sleep(1);
  }
  float2 r; r.x = __uint_as_float((unsigned)w0); r.y = __uint_as_float((unsigned)w1);
  return r;
}

__device__ __forceinline__ float4 poll4(const u64* p, unsigned tag){
  u64 w0, w1, w2, w3;
  for(;;){
    w0 = ldw(p); w1 = ldw(p+1); w2 = ldw(p+2); w3 = ldw(p+3);
    if ((unsigned)(w0 >> 32) >= tag && (unsigned)(w1 >> 32) >= tag &&
        (unsigned)(w2 >> 32) >= tag && (unsigned)(w3 >> 32) >= tag) break;
    __builtin_amdgcn_s_sleep(1);
  }
  float4 r;
  r.x = __uint_as_float((unsigned)w0); r.y = __uint_as_float((unsigned)w1);
  r.z = __uint_as_float((unsigned)w2); r.w = __uint_as_float((unsigned)w3);
  return r;
}

extern "C" __global__ __launch_bounds__(NTH, 1)
void trm_kernel(const float* __restrict__ x,   const float* __restrict__ h0,
                const float* __restrict__ wih, const float* __restrict__ whh,
                const float* __restrict__ bih, const float* __restrict__ bhh,
                const float* __restrict__ Lgw, const float* __restrict__ Lgb,
                const float* __restrict__ Ltw, const float* __restrict__ Ltb,
                const float* __restrict__ Luw, const float* __restrict__ Lub,
                const float* __restrict__ Hgw, const float* __restrict__ Hgb,
                const float* __restrict__ Htw, const float* __restrict__ Htb,
                const float* __restrict__ Huw, const float* __restrict__ Hub,
                float* __restrict__ out,
                u64* __restrict__ act_base)
{
  const int team = blockIdx.x & (TEAMS-1);
  const int j    = blockIdx.x / TEAMS;       // 0..31 slice id within team
  const int tid  = threadIdx.x;

  __shared__ float wgRZ[16][520];
  __shared__ float wgX[8][264];
  __shared__ float wgN[8][264];
  __shared__ float wclG[8][520], wclT[8][520];
  __shared__ float wchG[8][520], wchT[8][520];
  __shared__ float wul[8][264],  wuh[8][264];
  __shared__ float xst [BPT][256];
  __shared__ float st_o [BPT][256];
  __shared__ float st_zh[BPT][256];
  __shared__ float st_zl[BPT][256];
  __shared__ float st_h [BPT][256];
  __shared__ float bR[8],bZ[8],bX[8],bN[8],bCLg[8],bCLt[8],bCHg[8],bCHt[8],bUL[8],bUH[8];

  // ---------- one-time weight staging ----------
  {
    const int k = tid;
    for (int r=0;r<8;r++){
      const int nr = j*8+r;
      wgRZ[r][k]       = wih[(size_t)nr*256+k];
      wgRZ[r][256+k]   = whh[(size_t)nr*256+k];
      wgRZ[8+r][k]     = wih[(size_t)(256+nr)*256+k];
      wgRZ[8+r][256+k] = whh[(size_t)(256+nr)*256+k];
      wgX[r][k] = wih[(size_t)(512+nr)*256+k];
      wgN[r][k] = whh[(size_t)(512+nr)*256+k];
      wclG[r][k] = Lgw[(size_t)nr*512+k];  wclG[r][256+k] = Lgw[(size_t)nr*512+256+k];
      wclT[r][k] = Ltw[(size_t)nr*512+k];  wclT[r][256+k] = Ltw[(size_t)nr*512+256+k];
      wchG[r][k] = Hgw[(size_t)nr*512+k];  wchG[r][256+k] = Hgw[(size_t)nr*512+256+k];
      wchT[r][k] = Htw[(size_t)nr*512+k];  wchT[r][256+k] = Htw[(size_t)nr*512+256+k];
      wul[r][k] = Luw[(size_t)nr*256+k];
      wuh[r][k] = Huw[(size_t)nr*256+k];
    }
    if (tid<8){
      const int nr = j*8+tid;
      bR[tid]  = bih[nr]     + bhh[nr];
      bZ[tid]  = bih[256+nr] + bhh[256+nr];
      bX[tid]  = bih[512+nr];
      bN[tid]  = bhh[512+nr];
      bCLg[tid]= Lgb[nr];  bCLt[tid]= Ltb[nr];
      bCHg[tid]= Hgb[nr];  bCHt[tid]= Htb[nr];
      bUL[tid] = Lub[nr];  bUH[tid] = Hub[nr];
    }
    for (int u=tid; u<BPT*256; u+=NTH){
      const int b=u>>8, i=u&255;
      st_h[b][i]  = h0[(team*BPT+b)*256+i];
      st_o[b][i]  = 0.f;
      st_zh[b][i] = 0.f;
      st_zl[b][i] = 0.f;
    }
  }
  __syncthreads();

  u64* actT = act_base + (size_t)team*8192;  // 64KB/team; 2 x 2048-word buffers
  unsigned kst = 0;

  // C-cell: rows [8j,8j+8): u<8 gate rows, u>=8 tanh rows. K=512=[o|hid].
  auto cstage = [&](float (*WG)[520], float (*WT)[520], float* bG, float* bT,
                    float (*hid)[256], bool wout, int tt){
    const unsigned tag = kst + 1u;
    u64* buf = actT + (kst & 1u)*2048;
    WGBAR();                                   // prev-stage LDS state visible
    const int u = tid>>4, kk = tid&15, r = u&7;
    const bool isT = (u>=8);
    const float* wr = isT? WT[r] : WG[r];
    float a0=0.f, a1=0.f;
    #pragma unroll
    for (int i=0;i<16;i++){
      const float w = wr[kk+16*i];
      a0 += w*st_o[0][kk+16*i];
      a1 += w*st_o[1][kk+16*i];
    }
    #pragma unroll
    for (int i=0;i<16;i++){
      const float w = wr[256+kk+16*i];
      a0 += w*hid[0][kk+16*i];
      a1 += w*hid[1][kk+16*i];
    }
    a0 += __shfl_xor(a0,1); a0 += __shfl_xor(a0,2); a0 += __shfl_xor(a0,4); a0 += __shfl_xor(a0,8);
    a1 += __shfl_xor(a1,1); a1 += __shfl_xor(a1,2); a1 += __shfl_xor(a1,4); a1 += __shfl_xor(a1,8);
    if (kk==0){
      const float bb = isT? bT[r] : bG[r];
      const int n = j*8+r;
      stw(&buf[(0*256+n)*4 + (isT?1:0)], packw(a0+bb, tag));
      stw(&buf[(1*256+n)*4 + (isT?1:0)], packw(a1+bb, tag));
    }
    WGBAR();                                   // matvec LDS reads done before st_o update
    #pragma unroll
    for (int b=0;b<2;b++){
      float2 gt = poll2(&buf[(b*256+tid)*4], tag);
      const float g  = sigf(gt.x);
      const float rr = ftanh(gt.y);
      const float o  = g*rr + (1.f-g)*st_o[b][tid];
      st_o[b][tid] = o;
      if (wout) out[((size_t)(team*BPT+b)*SEQ + tt)*256 + tid] = o;
    }
    kst++;
  };

  // U-cell: 8 rows/WG, 32-lane units, K=256 over st_o; dst = tanh(pre).
  auto ustage = [&](float (*W)[264], float* bU, float (*dst)[256]){
    const unsigned tag = kst + 1u;
    u64* buf = actT + (kst & 1u)*2048;
    WGBAR();
    const int u = tid>>5, kk = tid&31;
    const float* wr = W[u];
    float a0=0.f, a1=0.f;
    #pragma unroll
    for (int i=0;i<8;i++){
      const float w = wr[kk+32*i];
      a0 += w*st_o[0][kk+32*i];
      a1 += w*st_o[1][kk+32*i];
    }
    a0 += __shfl_xor(a0,1); a0 += __shfl_xor(a0,2); a0 += __shfl_xor(a0,4); a0 += __shfl_xor(a0,8); a0 += __shfl_xor(a0,16);
    a1 += __shfl_xor(a1,1); a1 += __shfl_xor(a1,2); a1 += __shfl_xor(a1,4); a1 += __shfl_xor(a1,8); a1 += __shfl_xor(a1,16);
    if (kk==0){
      const int n = j*8+u;
      stw(&buf[(0*256+n)*4], packw(a0+bU[u], tag));
      stw(&buf[(1*256+n)*4], packw(a1+bU[u], tag));
    }
    WGBAR();
    #pragma unroll
    for (int b=0;b<2;b++){
      const float pre = poll1(&buf[(b*256+tid)*4], tag);
      dst[b][tid] = ftanh(pre);
    }
    kst++;
  };

  float px0 = x[((size_t)(team*BPT+0)*SEQ + 0)*256 + tid];
  float px1 = x[((size_t)(team*BPT+1)*SEQ + 0)*256 + tid];

  #pragma unroll 1
  for (int t=0; t<SEQ; ++t){
    // ---- GRU stage: slots {0:pr, 1:pz, 2:xn, 3:hn} per (b,i) ----
    {
      const unsigned tag = kst + 1u;
      u64* buf = actT + (kst & 1u)*2048;
      WGBAR();
      xst[0][tid] = px0;
      xst[1][tid] = px1;
      WGBAR();
      const int u = tid>>4, kk = tid&15, r = u&7;
      const int n = j*8+r;
      { // pass1: u<8 r-rows, u>=8 z-rows; K=512=[x|h]
        const bool isZ = (u>=8);
        const float* wr = wgRZ[u];
        float a0=0.f, a1=0.f;
        #pragma unroll
        for (int i=0;i<16;i++){
          const float w = wr[kk+16*i];
          a0 += w*xst[0][kk+16*i];
          a1 += w*xst[1][kk+16*i];
        }
        #pragma unroll
        for (int i=0;i<16;i++){
          const float w = wr[256+kk+16*i];
          a0 += w*st_h[0][kk+16*i];
          a1 += w*st_h[1][kk+16*i];
        }
        a0 += __shfl_xor(a0,1); a0 += __shfl_xor(a0,2); a0 += __shfl_xor(a0,4); a0 += __shfl_xor(a0,8);
        a1 += __shfl_xor(a1,1); a1 += __shfl_xor(a1,2); a1 += __shfl_xor(a1,4); a1 += __shfl_xor(a1,8);
        if (kk==0){
          const float bb = isZ? bZ[r] : bR[r];
          stw(&buf[(0*256+n)*4 + (isZ?1:0)], packw(a0+bb, tag));
          stw(&buf[(1*256+n)*4 + (isZ?1:0)], packw(a1+bb, tag));
        }
      }
      { // pass2: u<8 xn rows (src=x), u>=8 hn rows (src=h); K=256
        const bool isH = (u>=8);
        const float* wr = isH? wgN[r] : wgX[r];
        float (*src)[256] = isH? st_h : xst;
        float a0=0.f, a1=0.f;
        #pragma unroll
        for (int i=0;i<16;i++){
          const float w = wr[kk+16*i];
          a0 += w*src[0][kk+16*i];
          a1 += w*src[1][kk+16*i];
        }
        a0 += __shfl_xor(a0,1); a0 += __shfl_xor(a0,2); a0 += __shfl_xor(a0,4); a0 += __shfl_xor(a0,8);
        a1 += __shfl_xor(a1,1); a1 += __shfl_xor(a1,2); a1 += __shfl_xor(a1,4); a1 += __shfl_xor(a1,8);
        if (kk==0){
          const float bb = isH? bN[r] : bX[r];
          stw(&buf[(0*256+n)*4 + 2 + (isH?1:0)], packw(a0+bb, tag));
          stw(&buf[(1*256+n)*4 + 2 + (isH?1:0)], packw(a1+bb, tag));
        }
      }
      WGBAR();
      const bool last = (t==SEQ-1);
      #pragma unroll
      for (int b=0;b<2;b++){
        float4 p4 = poll4(&buf[(b*256+tid)*4], tag);  // (pr,pz,xn,hn)
        const float rg = sigf(p4.x);
        const float zg = sigf(p4.y);
        const float ng = ftanh(p4.z + rg*p4.w);
        const float hv = (1.f-zg)*ng + zg*st_h[b][tid];
        st_h[b][tid] = hv;
        st_o[b][tid] = hv;
        if (last) out[(size_t)NB*SEQ*256 + (team*BPT+b)*256 + tid] = hv;
      }
      if (t+1 < SEQ){
        px0 = x[((size_t)(team*BPT+0)*SEQ + (t+1))*256 + tid];
        px1 = x[((size_t)(team*BPT+1)*SEQ + (t+1))*256 + tid];
      }
      kst++;
    }
    // ---- refinement: 2 H-cycles of (3x L-cell, U_L, H-cell, U_H) ----
    #pragma unroll 1
    for (int c=0;c<2;c++){
      cstage(wclG,wclT,bCLg,bCLt,st_zh,false,t);
      cstage(wclG,wclT,bCLg,bCLt,st_zh,false,t);
      cstage(wclG,wclT,bCLg,bCLt,st_zh,false,t);
      ustage(wul,bUL,st_zl);
      cstage(wchG,wchT,bCHg,bCHt,st_zl,(c==1),t);
      ustage(wuh,bUH,st_zh);
    }
  }
}

extern "C" void kernel_launch(void* const* d_in, const int* in_sizes, int n_in,
                              void* d_out, int out_size, void* d_ws, size_t ws_size,
                              hipStream_t stream)
{
  // ws: [64KB, 64KB+512KB) tagged act buffers (64KB/team). Zeroed every launch
  // (tags must start below 1; harness poisons 0xAA).
  hipMemsetAsync(d_ws, 0, 65536 + (size_t)TEAMS*8192*sizeof(u64), stream);
  u64* act = (u64*)((char*)d_ws + 65536);

  dim3 grid(TEAMS*WPT), block(NTH);
  hipLaunchKernelGGL(trm_kernel, grid, block, 0, stream,
    (const float*)d_in[0],  (const float*)d_in[1],
    (const float*)d_in[2],  (const float*)d_in[3],
    (const float*)d_in[4],  (const float*)d_in[5],
    (const float*)d_in[6],  (const float*)d_in[7],
    (const float*)d_in[8],  (const float*)d_in[9],
    (const float*)d_in[10], (const float*)d_in[11],
    (const float*)d_in[12], (const float*)d_in[13],
    (const float*)d_in[14], (const float*)d_in[15],
    (const float*)d_in[16], (const float*)d_in[17],
    (float*)d_out, act);
}